// Round 1
// baseline (137.948 us; speedup 1.0000x reference)
//
#include <hip/hip_runtime.h>
#include <cstdint>
#include <cstddef>

// Problem dims
#define Bb 2
#define Tt 2048
#define Dd 1024
#define Hh 16
#define DHh 64

using short8 = __attribute__((ext_vector_type(8))) short;   // 8 bf16 (4 VGPRs) MFMA operand
using f32x4  = __attribute__((ext_vector_type(4))) float;   // MFMA accumulator
typedef unsigned short u16;

// f32 -> bf16 (RNE)
__device__ __forceinline__ u16 f2bf(float f) {
    unsigned int u = __float_as_uint(f);
    u += 0x7fffu + ((u >> 16) & 1u);
    return (u16)(u >> 16);
}

// async global->LDS, 16B per lane; LDS dest is wave-uniform base + lane*16
__device__ __forceinline__ void gload16(const void* g, void* l) {
    __builtin_amdgcn_global_load_lds((const __attribute__((address_space(1))) void*)g,
                                     (__attribute__((address_space(3))) void*)l, 16, 0, 0);
}

// ---------------------------------------------------------------------------
// Shared GEMM core: C[128x128] tile of A[M,K] @ BT[N,K]^T, bf16 in, f32 acc.
// Block 256 = 4 waves (2x2), each wave 64x64 = 4x4 frags of 16x16x32 MFMA.
// m97 structure: single LDS buffer, 2 barriers/K-step, global_load_lds w=16.
// ---------------------------------------------------------------------------
__device__ __forceinline__ void gemm_bt_core(const u16* __restrict__ A, const u16* __restrict__ BT,
                                             int K, int m0, int n0,
                                             u16* As, u16* Bs, f32x4 acc[4][4]) {
    const int tid = threadIdx.x;
    const int w = tid >> 6, lane = tid & 63;
    const int lr = lane & 15, lg = lane >> 4;
    const int wr = w >> 1, wc = w & 1;
    const int arow = lane >> 2;          // 0..15 within 16-row staging group
    const int acol = (lane & 3) * 8;     // k-chunk offset (elems)
    for (int kk = 0; kk < K; kk += 32) {
        __syncthreads();   // previous tile's reads complete before overwrite
#pragma unroll
        for (int j = 0; j < 2; ++j) {
            int r0 = w * 32 + j * 16;
            gload16(A  + (size_t)(m0 + r0 + arow) * K + kk + acol, (char*)As + r0 * 64);
            gload16(BT + (size_t)(n0 + r0 + arow) * K + kk + acol, (char*)Bs + r0 * 64);
        }
        __syncthreads();   // staging visible (drains vmcnt)
        short8 af[4], bfv[4];
#pragma unroll
        for (int m = 0; m < 4; ++m)
            af[m] = *(const short8*)((const char*)As + ((wr * 64 + m * 16 + lr) * 64 + lg * 16));
#pragma unroll
        for (int n = 0; n < 4; ++n)
            bfv[n] = *(const short8*)((const char*)Bs + ((wc * 64 + n * 16 + lr) * 64 + lg * 16));
#pragma unroll
        for (int m = 0; m < 4; ++m)
#pragma unroll
            for (int n = 0; n < 4; ++n)
                acc[m][n] = __builtin_amdgcn_mfma_f32_16x16x32_bf16(af[m], bfv[n], acc[m][n], 0, 0, 0);
    }
}

// ---------------------------------------------------------------------------
// Prep: x (f32) -> bf16
// ---------------------------------------------------------------------------
__global__ __launch_bounds__(256) void convert_x_k(const float4* __restrict__ x4,
                                                   ushort4* __restrict__ xb4, int n4) {
    int i = blockIdx.x * 256 + threadIdx.x;
    if (i >= n4) return;
    float4 v = x4[i];
    ushort4 o;
    o.x = f2bf(v.x); o.y = f2bf(v.y); o.z = f2bf(v.z); o.w = f2bf(v.w);
    xb4[i] = o;
}

// Prep: W[k][n] f32 -> WT[n][k] bf16, 4 matrices (z: Wq,Wk,Wv,Wp)
__global__ void transpose_w_k(const float* __restrict__ Wq, const float* __restrict__ Wk,
                              const float* __restrict__ Wv, const float* __restrict__ Wp,
                              u16* __restrict__ wt) {
    __shared__ float tile[32][33];
    const int z = blockIdx.z;
    const float* W = (z == 0) ? Wq : (z == 1) ? Wk : (z == 2) ? Wv : Wp;
    const int n0 = blockIdx.x * 32, k0 = blockIdx.y * 32;
    const int tx = threadIdx.x, ty = threadIdx.y;   // (32, 8)
#pragma unroll
    for (int j = 0; j < 4; ++j)
        tile[ty + j * 8][tx] = W[(size_t)(k0 + ty + j * 8) * Dd + n0 + tx];
    __syncthreads();
    u16* outp = wt + (size_t)z * Dd * Dd;
#pragma unroll
    for (int j = 0; j < 4; ++j)
        outp[(size_t)(n0 + ty + j * 8) * Dd + k0 + tx] = f2bf(tile[tx][ty + j * 8]);
}

// ---------------------------------------------------------------------------
// QKV GEMM: [4096,1024] @ [1024,3072] -> Q (scaled, per-head), K (per-head),
// V transposed per-head [bh][dh][t].
// ---------------------------------------------------------------------------
__global__ __launch_bounds__(256) void qkv_gemm_k(const u16* __restrict__ xb, const u16* __restrict__ wt,
        const float* __restrict__ bq, const float* __restrict__ bk, const float* __restrict__ bv,
        u16* __restrict__ Qg, u16* __restrict__ Kg, u16* __restrict__ VTg) {
    __shared__ alignas(16) u16 As[128 * 32];
    __shared__ alignas(16) u16 Bs[128 * 32];
    f32x4 acc[4][4];
    const f32x4 vzero = {0.f, 0.f, 0.f, 0.f};
#pragma unroll
    for (int m = 0; m < 4; ++m)
#pragma unroll
        for (int n = 0; n < 4; ++n) acc[m][n] = vzero;
    const int m0 = blockIdx.y * 128, n0 = blockIdx.x * 128;
    gemm_bt_core(xb, wt, 1024, m0, n0, As, Bs, acc);
    const int tid = threadIdx.x, w = tid >> 6, lane = tid & 63, lr = lane & 15, lg = lane >> 4;
    const int wr = w >> 1, wc = w & 1;
    const int sec = n0 >> 10;             // 0:Q 1:K 2:V (128-tiles never straddle)
    const float* bias = (sec == 0) ? bq : (sec == 1) ? bk : bv;
    u16* dst = (sec == 0) ? Qg : (sec == 1) ? Kg : VTg;
    const float qscale = (sec == 0) ? 0.125f : 1.0f;   // DH^-0.5
#pragma unroll
    for (int n = 0; n < 4; ++n) {
        int gn = n0 + wc * 64 + n * 16 + lr;
        int j = gn & 1023;
        float bj = bias[j];
        int h = j >> 6, dh = j & 63;
#pragma unroll
        for (int m = 0; m < 4; ++m) {
            int gmb = m0 + wr * 64 + m * 16 + 4 * lg;
#pragma unroll
            for (int i = 0; i < 4; ++i) {
                int gm = gmb + i;
                int b = gm >> 11, t = gm & 2047;
                float v = (acc[m][n][i] + bj) * qscale;
                size_t off;
                if (sec < 2) off = (((size_t)(b * Hh + h)) * Tt + t) * DHh + dh;       // [bh][t][dh]
                else         off = (((size_t)(b * Hh + h)) * DHh + dh) * Tt + t;       // [bh][dh][t]
                dst[off] = f2bf(v);
            }
        }
    }
}

// ---------------------------------------------------------------------------
// Flash attention: block = 4 waves, 64 q-rows (wave owns 16), K-tile = 128.
// K/VT/P LDS tiles XOR-chunk-swizzled (c ^= r&7) against 16-way conflicts;
// staging pre-swizzles the GLOBAL source (global_load_lds dest stays linear).
// Online softmax with -1e30 sentinel: fully-masked rows stay finite and are
// zeroed by the final data-mask multiply (matches nan_to_num semantics).
// ---------------------------------------------------------------------------
__global__ __launch_bounds__(256) void attn_k(const u16* __restrict__ Qg, const u16* __restrict__ Kg,
        const u16* __restrict__ VTg, const int* __restrict__ dmask, u16* __restrict__ Og) {
    __shared__ alignas(16) u16 Ks[128 * 64];     // [key][dh]   rows 128B, swz
    __shared__ alignas(16) u16 Vs[64 * 128];     // [dh][key]   rows 256B, swz
    __shared__ alignas(16) u16 Ps[4][16 * 128];  // per-wave P  rows 256B, swz
    const int bh = blockIdx.x;
    const int qb = (int)gridDim.y - 1 - (int)blockIdx.y;  // heavy (high-q) blocks first
    const int b = bh >> 4, h = bh & 15;
    const int tid = threadIdx.x, w = tid >> 6, lane = tid & 63;
    const int lr = lane & 15, lg = lane >> 4;
    const int q0 = qb * 64 + w * 16;
    const u16* Qbase = Qg + ((size_t)bh * Tt + q0) * DHh;
    short8 qf0 = *(const short8*)(Qbase + lr * DHh + lg * 8);
    short8 qf1 = *(const short8*)(Qbase + lr * DHh + 32 + lg * 8);
    const f32x4 vzero = {0.f, 0.f, 0.f, 0.f};
    float mrow[4], lrow[4];
    f32x4 o[4];
#pragma unroll
    for (int i = 0; i < 4; ++i) { mrow[i] = -1e30f; lrow[i] = 0.f; }
#pragma unroll
    for (int n = 0; n < 4; ++n) o[n] = vzero;
    int qrow[4];
#pragma unroll
    for (int i = 0; i < 4; ++i) qrow[i] = q0 + 4 * lg + i;
    const int ktiles = (qb * 64 + 63) / 128 + 1;
    char* KsB = (char*)Ks; char* VsB = (char*)Vs; char* PsB = (char*)&Ps[w][0];

    for (int kt = 0; kt < ktiles; ++kt) {
        const int kbase = kt * 128;
        __syncthreads();
        // stage K tile: wave w rows [w*32, w*32+32), 8 rows (128B each) per instr
#pragma unroll
        for (int j = 0; j < 4; ++j) {
            int r0 = w * 32 + j * 8;
            int r = r0 + (lane >> 3);
            int cs = (lane & 7) ^ (r & 7);
            gload16(Kg + ((size_t)bh * Tt + kbase + r) * DHh + cs * 8, KsB + r0 * 128);
        }
        // stage VT tile: wave w rows [w*16, w*16+16), 4 rows (256B each) per instr
#pragma unroll
        for (int j = 0; j < 4; ++j) {
            int r0 = w * 16 + j * 4;
            int r = r0 + (lane >> 4);
            int cs = (lane & 15) ^ (r & 7);
            gload16(VTg + ((size_t)bh * DHh + r) * Tt + kbase + cs * 8, VsB + r0 * 256);
        }
        __syncthreads();
        // S = Q K^T : 8 key-frags x 2 k-steps
        f32x4 s[8];
#pragma unroll
        for (int nf = 0; nf < 8; ++nf) {
            int r = nf * 16 + lr;
            short8 k0v = *(const short8*)(KsB + r * 128 + (((0 + lg) ^ (r & 7)) << 4));
            short8 k1v = *(const short8*)(KsB + r * 128 + (((4 + lg) ^ (r & 7)) << 4));
            f32x4 t0 = __builtin_amdgcn_mfma_f32_16x16x32_bf16(qf0, k0v, vzero, 0, 0, 0);
            s[nf] = __builtin_amdgcn_mfma_f32_16x16x32_bf16(qf1, k1v, t0, 0, 0, 0);
        }
        // causal + data mask
        int mk[8];
#pragma unroll
        for (int nf = 0; nf < 8; ++nf) mk[nf] = dmask[b * Tt + kbase + nf * 16 + lr];
#pragma unroll
        for (int nf = 0; nf < 8; ++nf) {
            int tk = kbase + nf * 16 + lr;
#pragma unroll
            for (int i = 0; i < 4; ++i) {
                if (!((mk[nf] != 0) && (tk <= qrow[i]))) s[nf][i] = -1e30f;
            }
        }
        // online softmax (row = 4*lg+i, cols spread over lr -> shfl over 16 lanes)
#pragma unroll
        for (int i = 0; i < 4; ++i) {
            float rm = s[0][i];
#pragma unroll
            for (int nf = 1; nf < 8; ++nf) rm = fmaxf(rm, s[nf][i]);
            rm = fmaxf(rm, __shfl_xor(rm, 1));
            rm = fmaxf(rm, __shfl_xor(rm, 2));
            rm = fmaxf(rm, __shfl_xor(rm, 4));
            rm = fmaxf(rm, __shfl_xor(rm, 8));
            float mn = fmaxf(mrow[i], rm);
            float sc = __expf(mrow[i] - mn);
            mrow[i] = mn;
            lrow[i] *= sc;
#pragma unroll
            for (int n = 0; n < 4; ++n) o[n][i] *= sc;
            float rs = 0.f;
#pragma unroll
            for (int nf = 0; nf < 8; ++nf) { float p = __expf(s[nf][i] - mn); s[nf][i] = p; rs += p; }
            rs += __shfl_xor(rs, 1); rs += __shfl_xor(rs, 2);
            rs += __shfl_xor(rs, 4); rs += __shfl_xor(rs, 8);
            lrow[i] += rs;
        }
        // P -> per-wave LDS (bf16, swizzled), D-layout -> A-layout reshape
#pragma unroll
        for (int nf = 0; nf < 8; ++nf) {
            int colc = nf * 2 + (lr >> 3);
            int ce = lr & 7;
#pragma unroll
            for (int i = 0; i < 4; ++i) {
                int r = 4 * lg + i;
                *(u16*)(PsB + r * 256 + (((colc ^ (r & 7))) << 4) + (ce << 1)) = f2bf(s[nf][i]);
            }
        }
        // O += P @ V : 4 k-steps x 4 dh-frags
#pragma unroll
        for (int ks = 0; ks < 4; ++ks) {
            short8 pf = *(const short8*)(PsB + lr * 256 + ((((ks * 4 + lg)) ^ (lr & 7)) << 4));
#pragma unroll
            for (int n = 0; n < 4; ++n) {
                int rv = n * 16 + lr;
                short8 vf = *(const short8*)(VsB + rv * 256 + ((((ks * 4 + lg)) ^ (rv & 7)) << 4));
                o[n] = __builtin_amdgcn_mfma_f32_16x16x32_bf16(pf, vf, o[n], 0, 0, 0);
            }
        }
    }
    // epilogue: normalize, write O[t][h*64+dh] bf16
#pragma unroll
    for (int i = 0; i < 4; ++i) {
        float inv = lrow[i] > 0.f ? 1.0f / lrow[i] : 0.f;
#pragma unroll
        for (int n = 0; n < 4; ++n) {
            Og[((size_t)(b * Tt + qrow[i])) * Dd + h * DHh + n * 16 + lr] = f2bf(o[n][i] * inv);
        }
    }
}

// ---------------------------------------------------------------------------
// Output GEMM: O[4096,1024] @ Wp -> f32 out, + bp, * data_mask
// ---------------------------------------------------------------------------
__global__ __launch_bounds__(256) void out_gemm_k(const u16* __restrict__ Og, const u16* __restrict__ wpt,
        const float* __restrict__ bp, const int* __restrict__ dmask, float* __restrict__ out) {
    __shared__ alignas(16) u16 As[128 * 32];
    __shared__ alignas(16) u16 Bs[128 * 32];
    f32x4 acc[4][4];
    const f32x4 vzero = {0.f, 0.f, 0.f, 0.f};
#pragma unroll
    for (int m = 0; m < 4; ++m)
#pragma unroll
        for (int n = 0; n < 4; ++n) acc[m][n] = vzero;
    const int m0 = blockIdx.y * 128, n0 = blockIdx.x * 128;
    gemm_bt_core(Og, wpt, 1024, m0, n0, As, Bs, acc);
    const int tid = threadIdx.x, w = tid >> 6, lane = tid & 63, lr = lane & 15, lg = lane >> 4;
    const int wr = w >> 1, wc = w & 1;
#pragma unroll
    for (int n = 0; n < 4; ++n) {
        int gn = n0 + wc * 64 + n * 16 + lr;
        float bj = bp[gn];
#pragma unroll
        for (int m = 0; m < 4; ++m) {
            int gmb = m0 + wr * 64 + m * 16 + 4 * lg;
#pragma unroll
            for (int i = 0; i < 4; ++i) {
                int gm = gmb + i;
                float dmv = (float)dmask[gm];
                out[(size_t)gm * Dd + gn] = (acc[m][n][i] + bj) * dmv;
            }
        }
    }
}

// ---------------------------------------------------------------------------
// Workspace layout (bytes):
//   [0,8M)    xb  bf16 [4096][1024]   (reused as Og after qkv_gemm)
//   [8M,16M)  wt  bf16 [4][1024][1024] (WqT,WkT,WvT,WpT)
//   [16M,24M) Qg  bf16 [32][2048][64]  (scaled)
//   [24M,32M) Kg  bf16 [32][2048][64]
//   [32M,40M) VTg bf16 [32][64][2048]
// ---------------------------------------------------------------------------
extern "C" void kernel_launch(void* const* d_in, const int* in_sizes, int n_in,
                              void* d_out, int out_size, void* d_ws, size_t ws_size,
                              hipStream_t stream) {
    const float* x   = (const float*)d_in[0];
    const int*  dmask = (const int*)d_in[1];
    const float* Wq = (const float*)d_in[2];
    const float* bq = (const float*)d_in[3];
    const float* Wk = (const float*)d_in[4];
    const float* bk = (const float*)d_in[5];
    const float* Wv = (const float*)d_in[6];
    const float* bv = (const float*)d_in[7];
    const float* Wp = (const float*)d_in[8];
    const float* bp = (const float*)d_in[9];
    float* out = (float*)d_out;
    char* ws = (char*)d_ws;
    u16* xb  = (u16*)(ws);
    u16* wt  = (u16*)(ws + ((size_t)8 << 20));
    u16* Qg  = (u16*)(ws + ((size_t)16 << 20));
    u16* Kg  = (u16*)(ws + ((size_t)24 << 20));
    u16* VTg = (u16*)(ws + ((size_t)32 << 20));
    u16* Og  = xb;   // reuse: xb consumed by qkv_gemm before attn writes Og

    convert_x_k<<<dim3(4096), dim3(256), 0, stream>>>((const float4*)x, (ushort4*)xb, (Bb * Tt * Dd) / 4);
    transpose_w_k<<<dim3(32, 32, 4), dim3(32, 8), 0, stream>>>(Wq, Wk, Wv, Wp, wt);
    qkv_gemm_k<<<dim3(24, 32), dim3(256), 0, stream>>>(xb, wt, bq, bk, bv, Qg, Kg, VTg);
    attn_k<<<dim3(32, 32), dim3(256), 0, stream>>>(Qg, Kg, VTg, dmask, Og);
    out_gemm_k<<<dim3(8, 32), dim3(256), 0, stream>>>(Og, wt + (size_t)3 * Dd * Dd, bp, dmask, out);
}

// Round 2
// 132.272 us; speedup vs baseline: 1.0429x; 1.0429x over previous
//
#include <hip/hip_runtime.h>
#include <hip/hip_bf16.h>
#include <cstdint>
#include <cstddef>

// Problem dims
#define Bb 2
#define Tt 2048
#define Dd 1024
#define Hh 16
#define DHh 64

using short8 = __attribute__((ext_vector_type(8))) short;   // 8 bf16 (4 VGPRs) MFMA operand
using f32x4  = __attribute__((ext_vector_type(4))) float;   // MFMA accumulator
typedef unsigned short u16;

// f32 -> bf16 (RNE) scalar
__device__ __forceinline__ u16 f2bf(float f) {
    unsigned int u = __float_as_uint(f);
    u += 0x7fffu + ((u >> 16) & 1u);
    return (u16)(u >> 16);
}

// pack two f32 -> bf16x2 (v_cvt_pk_bf16_f32 via HIP API)
__device__ __forceinline__ unsigned int pk2bf(float a, float b) {
    union { __hip_bfloat162 h; unsigned int u; } c;
    c.h = __float22bfloat162_rn(float2{a, b});
    return c.u;
}

// async global->LDS, 16B per lane; LDS dest is wave-uniform base + lane*16
__device__ __forceinline__ void gload16(const void* g, void* l) {
    __builtin_amdgcn_global_load_lds((const __attribute__((address_space(1))) void*)g,
                                     (__attribute__((address_space(3))) void*)l, 16, 0, 0);
}

// ---------------------------------------------------------------------------
// Shared GEMM core: C[128x128] tile of A[M,K] @ BT[N,K]^T, bf16 in, f32 acc.
// ---------------------------------------------------------------------------
__device__ __forceinline__ void gemm_bt_core(const u16* __restrict__ A, const u16* __restrict__ BT,
                                             int K, int m0, int n0,
                                             u16* As, u16* Bs, f32x4 acc[4][4]) {
    const int tid = threadIdx.x;
    const int w = tid >> 6, lane = tid & 63;
    const int lr = lane & 15, lg = lane >> 4;
    const int wr = w >> 1, wc = w & 1;
    const int arow = lane >> 2;          // 0..15 within 16-row staging group
    const int acol = (lane & 3) * 8;     // k-chunk offset (elems)
    for (int kk = 0; kk < K; kk += 32) {
        __syncthreads();   // previous tile's reads complete before overwrite
#pragma unroll
        for (int j = 0; j < 2; ++j) {
            int r0 = w * 32 + j * 16;
            gload16(A  + (size_t)(m0 + r0 + arow) * K + kk + acol, (char*)As + r0 * 64);
            gload16(BT + (size_t)(n0 + r0 + arow) * K + kk + acol, (char*)Bs + r0 * 64);
        }
        __syncthreads();   // staging visible (drains vmcnt)
        short8 af[4], bfv[4];
#pragma unroll
        for (int m = 0; m < 4; ++m)
            af[m] = *(const short8*)((const char*)As + ((wr * 64 + m * 16 + lr) * 64 + lg * 16));
#pragma unroll
        for (int n = 0; n < 4; ++n)
            bfv[n] = *(const short8*)((const char*)Bs + ((wc * 64 + n * 16 + lr) * 64 + lg * 16));
#pragma unroll
        for (int m = 0; m < 4; ++m)
#pragma unroll
            for (int n = 0; n < 4; ++n)
                acc[m][n] = __builtin_amdgcn_mfma_f32_16x16x32_bf16(af[m], bfv[n], acc[m][n], 0, 0, 0);
    }
}

// ---------------------------------------------------------------------------
// Prep: x (f32) -> bf16
// ---------------------------------------------------------------------------
__global__ __launch_bounds__(256) void convert_x_k(const float4* __restrict__ x4,
                                                   ushort4* __restrict__ xb4, int n4) {
    int i = blockIdx.x * 256 + threadIdx.x;
    if (i >= n4) return;
    float4 v = x4[i];
    ushort4 o;
    o.x = f2bf(v.x); o.y = f2bf(v.y); o.z = f2bf(v.z); o.w = f2bf(v.w);
    xb4[i] = o;
}

// Prep: W[k][n] f32 -> WT[n][k] bf16, 4 matrices (z: Wq,Wk,Wv,Wp)
__global__ void transpose_w_k(const float* __restrict__ Wq, const float* __restrict__ Wk,
                              const float* __restrict__ Wv, const float* __restrict__ Wp,
                              u16* __restrict__ wt) {
    __shared__ float tile[32][33];
    const int z = blockIdx.z;
    const float* W = (z == 0) ? Wq : (z == 1) ? Wk : (z == 2) ? Wv : Wp;
    const int n0 = blockIdx.x * 32, k0 = blockIdx.y * 32;
    const int tx = threadIdx.x, ty = threadIdx.y;   // (32, 8)
#pragma unroll
    for (int j = 0; j < 4; ++j)
        tile[ty + j * 8][tx] = W[(size_t)(k0 + ty + j * 8) * Dd + n0 + tx];
    __syncthreads();
    u16* outp = wt + (size_t)z * Dd * Dd;
#pragma unroll
    for (int j = 0; j < 4; ++j)
        outp[(size_t)(n0 + ty + j * 8) * Dd + k0 + tx] = f2bf(tile[tx][ty + j * 8]);
}

// ---------------------------------------------------------------------------
// QKV GEMM: [4096,1024] @ [1024,3072] -> Q (scaled incl log2e, per-head),
// K (per-head), V transposed per-head [bh][dh][t].
// ---------------------------------------------------------------------------
__global__ __launch_bounds__(256) void qkv_gemm_k(const u16* __restrict__ xb, const u16* __restrict__ wt,
        const float* __restrict__ bq, const float* __restrict__ bk, const float* __restrict__ bv,
        u16* __restrict__ Qg, u16* __restrict__ Kg, u16* __restrict__ VTg) {
    __shared__ alignas(16) u16 As[128 * 32];
    __shared__ alignas(16) u16 Bs[128 * 32];
    f32x4 acc[4][4];
    const f32x4 vzero = {0.f, 0.f, 0.f, 0.f};
#pragma unroll
    for (int m = 0; m < 4; ++m)
#pragma unroll
        for (int n = 0; n < 4; ++n) acc[m][n] = vzero;
    const int m0 = blockIdx.y * 128, n0 = blockIdx.x * 128;
    gemm_bt_core(xb, wt, 1024, m0, n0, As, Bs, acc);
    const int tid = threadIdx.x, w = tid >> 6, lane = tid & 63, lr = lane & 15, lg = lane >> 4;
    const int wr = w >> 1, wc = w & 1;
    const int sec = n0 >> 10;             // 0:Q 1:K 2:V (128-tiles never straddle)
    const float* bias = (sec == 0) ? bq : (sec == 1) ? bk : bv;
    u16* dst = (sec == 0) ? Qg : (sec == 1) ? Kg : VTg;
    // Q scale: DH^-0.5 * log2(e)  -> softmax runs in exp2 domain
    const float qscale = (sec == 0) ? 0.125f * 1.4426950408889634f : 1.0f;
#pragma unroll
    for (int n = 0; n < 4; ++n) {
        int gn = n0 + wc * 64 + n * 16 + lr;
        int j = gn & 1023;
        float bj = bias[j];
        int h = j >> 6, dh = j & 63;
#pragma unroll
        for (int m = 0; m < 4; ++m) {
            int gmb = m0 + wr * 64 + m * 16 + 4 * lg;
#pragma unroll
            for (int i = 0; i < 4; ++i) {
                int gm = gmb + i;
                int b = gm >> 11, t = gm & 2047;
                float v = (acc[m][n][i] + bj) * qscale;
                size_t off;
                if (sec < 2) off = (((size_t)(b * Hh + h)) * Tt + t) * DHh + dh;       // [bh][t][dh]
                else         off = (((size_t)(b * Hh + h)) * DHh + dh) * Tt + t;       // [bh][dh][t]
                dst[off] = f2bf(v);
            }
        }
    }
}

// ---------------------------------------------------------------------------
// Flash attention, swapped-operand form:
//   S^T = mfma(K, Q)  -> lane holds S[k][q=lane&15], k = 16*nf + 4*lg + i
//   O^T = mfma(V, P)  -> lane holds O[dh][q=lane&15]
// Softmax is per-lane over 32 in-register values + 2 shfl_xor (16,32).
// Masking is multiplicative post-exp (shift-invariant softmax; fully-masked
// rows give l=0 -> inv=0, matching nan_to_num + final data-mask multiply).
// P packed via v_cvt_pk_bf16_f32, 8B swizzled ds_writes.
// ---------------------------------------------------------------------------
__global__ __launch_bounds__(256) void attn_k(const u16* __restrict__ Qg, const u16* __restrict__ Kg,
        const u16* __restrict__ VTg, const int* __restrict__ dmask, u16* __restrict__ Og) {
    __shared__ alignas(16) u16 Ks[128 * 64];     // [key][dh]   rows 128B, swz
    __shared__ alignas(16) u16 Vs[64 * 128];     // [dh][key]   rows 256B, swz
    __shared__ alignas(16) u16 Ps[4][16 * 128];  // per-wave P  rows 256B, swz
    const int bh = blockIdx.x;
    const int qb = (int)gridDim.y - 1 - (int)blockIdx.y;  // heavy (high-q) blocks first
    const int b = bh >> 4, h = bh & 15;
    const int tid = threadIdx.x, w = tid >> 6, lane = tid & 63;
    const int lr = lane & 15, lg = lane >> 4;
    const int q0 = qb * 64 + w * 16;
    const int qrow = q0 + lr;                    // this lane's q row
    const u16* Qbase = Qg + ((size_t)bh * Tt + q0) * DHh;
    short8 qf0 = *(const short8*)(Qbase + lr * DHh + lg * 8);
    short8 qf1 = *(const short8*)(Qbase + lr * DHh + 32 + lg * 8);
    const f32x4 vzero = {0.f, 0.f, 0.f, 0.f};
    float mrow = -1e30f, lrow = 0.f;
    f32x4 o[4];
#pragma unroll
    for (int n = 0; n < 4; ++n) o[n] = vzero;
    const int ktiles = (qb * 64 + 63) / 128 + 1;
    char* KsB = (char*)Ks; char* VsB = (char*)Vs; char* PsB = (char*)&Ps[w][0];

    for (int kt = 0; kt < ktiles; ++kt) {
        const int kbase = kt * 128;
        __syncthreads();
        // stage K tile: wave w rows [w*32, w*32+32), 8 rows (128B each) per instr
#pragma unroll
        for (int j = 0; j < 4; ++j) {
            int r0 = w * 32 + j * 8;
            int r = r0 + (lane >> 3);
            int cs = (lane & 7) ^ (r & 7);
            gload16(Kg + ((size_t)bh * Tt + kbase + r) * DHh + cs * 8, KsB + r0 * 128);
        }
        // stage VT tile: wave w rows [w*16, w*16+16), 4 rows (256B each) per instr
#pragma unroll
        for (int j = 0; j < 4; ++j) {
            int r0 = w * 16 + j * 4;
            int r = r0 + (lane >> 4);
            int cs = (lane & 15) ^ (r & 7);
            gload16(VTg + ((size_t)bh * DHh + r) * Tt + kbase + cs * 8, VsB + r0 * 256);
        }
        __syncthreads();
        // S^T = K Q^T : lane q = lr, k = 16*nf + 4*lg + i
        f32x4 s[8];
#pragma unroll
        for (int nf = 0; nf < 8; ++nf) {
            int r = nf * 16 + lr;
            short8 k0v = *(const short8*)(KsB + r * 128 + (((0 + lg) ^ (r & 7)) << 4));
            short8 k1v = *(const short8*)(KsB + r * 128 + (((4 + lg) ^ (r & 7)) << 4));
            f32x4 t0 = __builtin_amdgcn_mfma_f32_16x16x32_bf16(k0v, qf0, vzero, 0, 0, 0);
            s[nf] = __builtin_amdgcn_mfma_f32_16x16x32_bf16(k1v, qf1, t0, 0, 0, 0);
        }
        // data mask (int4 -> float 0/1), causal only on diagonal tiles
        float4 km[8];
        {
            const int4* dmv = (const int4*)(dmask + (size_t)b * Tt + kbase);
#pragma unroll
            for (int nf = 0; nf < 8; ++nf) {
                int4 mi = dmv[4 * nf + lg];
                km[nf] = make_float4((float)mi.x, (float)mi.y, (float)mi.z, (float)mi.w);
            }
        }
        if (kbase + 127 > q0) {   // wave-uniform diagonal check
#pragma unroll
            for (int nf = 0; nf < 8; ++nf) {
                int tk = kbase + 16 * nf + 4 * lg;
                if (tk + 0 > qrow) km[nf].x = 0.f;
                if (tk + 1 > qrow) km[nf].y = 0.f;
                if (tk + 2 > qrow) km[nf].z = 0.f;
                if (tk + 3 > qrow) km[nf].w = 0.f;
            }
        }
        // row max: in-lane tree over 32 raw scores + 2 shfl (lanes sharing lr)
        float rm;
        {
            f32x4 m4 = s[0];
#pragma unroll
            for (int nf = 1; nf < 8; ++nf) {
                m4[0] = fmaxf(m4[0], s[nf][0]); m4[1] = fmaxf(m4[1], s[nf][1]);
                m4[2] = fmaxf(m4[2], s[nf][2]); m4[3] = fmaxf(m4[3], s[nf][3]);
            }
            rm = fmaxf(fmaxf(m4[0], m4[1]), fmaxf(m4[2], m4[3]));
            rm = fmaxf(rm, __shfl_xor(rm, 16));
            rm = fmaxf(rm, __shfl_xor(rm, 32));
        }
        float mn = fmaxf(mrow, rm);
        float sc = exp2f(mrow - mn);
        mrow = mn;
        lrow *= sc;
#pragma unroll
        for (int n = 0; n < 4; ++n) {
            o[n][0] *= sc; o[n][1] *= sc; o[n][2] *= sc; o[n][3] *= sc;
        }
        // P = exp2(S - m) * mask; pack 4 consecutive k -> 8B swizzled ds_write
        float rs = 0.f;
#pragma unroll
        for (int nf = 0; nf < 8; ++nf) {
            float p0 = exp2f(s[nf][0] - mn) * km[nf].x;
            float p1 = exp2f(s[nf][1] - mn) * km[nf].y;
            float p2 = exp2f(s[nf][2] - mn) * km[nf].z;
            float p3 = exp2f(s[nf][3] - mn) * km[nf].w;
            rs += (p0 + p1) + (p2 + p3);
            uint2 pw;
            pw.x = pk2bf(p0, p1);
            pw.y = pk2bf(p2, p3);
            *(uint2*)(PsB + lr * 256 + ((((2 * nf + (lg >> 1)) ^ (lr & 7))) << 4) + ((lg & 1) << 3)) = pw;
        }
        rs += __shfl_xor(rs, 16);
        rs += __shfl_xor(rs, 32);
        lrow += rs;
        // O^T += V^T P^T : 4 k-steps x 4 dh-frags
#pragma unroll
        for (int ks = 0; ks < 4; ++ks) {
            short8 pf = *(const short8*)(PsB + lr * 256 + ((((ks * 4 + lg)) ^ (lr & 7)) << 4));
#pragma unroll
            for (int n = 0; n < 4; ++n) {
                int rv = n * 16 + lr;
                short8 vf = *(const short8*)(VsB + rv * 256 + ((((ks * 4 + lg)) ^ (rv & 7)) << 4));
                o[n] = __builtin_amdgcn_mfma_f32_16x16x32_bf16(vf, pf, o[n], 0, 0, 0);
            }
        }
    }
    // epilogue: normalize, write O[t=qrow][h*64 + dh], dh = n*16 + 4*lg + i
    float inv = lrow > 0.f ? 1.0f / lrow : 0.f;
#pragma unroll
    for (int n = 0; n < 4; ++n) {
        uint2 pw;
        pw.x = pk2bf(o[n][0] * inv, o[n][1] * inv);
        pw.y = pk2bf(o[n][2] * inv, o[n][3] * inv);
        *(uint2*)(Og + ((size_t)(b * Tt + qrow)) * Dd + h * DHh + n * 16 + 4 * lg) = pw;
    }
}

// ---------------------------------------------------------------------------
// Output GEMM: O[4096,1024] @ Wp -> f32 out, + bp, * data_mask
// ---------------------------------------------------------------------------
__global__ __launch_bounds__(256) void out_gemm_k(const u16* __restrict__ Og, const u16* __restrict__ wpt,
        const float* __restrict__ bp, const int* __restrict__ dmask, float* __restrict__ out) {
    __shared__ alignas(16) u16 As[128 * 32];
    __shared__ alignas(16) u16 Bs[128 * 32];
    f32x4 acc[4][4];
    const f32x4 vzero = {0.f, 0.f, 0.f, 0.f};
#pragma unroll
    for (int m = 0; m < 4; ++m)
#pragma unroll
        for (int n = 0; n < 4; ++n) acc[m][n] = vzero;
    const int m0 = blockIdx.y * 128, n0 = blockIdx.x * 128;
    gemm_bt_core(Og, wpt, 1024, m0, n0, As, Bs, acc);
    const int tid = threadIdx.x, w = tid >> 6, lane = tid & 63, lr = lane & 15, lg = lane >> 4;
    const int wr = w >> 1, wc = w & 1;
#pragma unroll
    for (int n = 0; n < 4; ++n) {
        int gn = n0 + wc * 64 + n * 16 + lr;
        float bj = bp[gn];
#pragma unroll
        for (int m = 0; m < 4; ++m) {
            int gmb = m0 + wr * 64 + m * 16 + 4 * lg;
#pragma unroll
            for (int i = 0; i < 4; ++i) {
                int gm = gmb + i;
                float dmv = (float)dmask[gm];
                out[(size_t)gm * Dd + gn] = (acc[m][n][i] + bj) * dmv;
            }
        }
    }
}

// ---------------------------------------------------------------------------
// Workspace layout (bytes):
//   [0,8M)    xb  bf16 [4096][1024]   (reused as Og after qkv_gemm)
//   [8M,16M)  wt  bf16 [4][1024][1024] (WqT,WkT,WvT,WpT)
//   [16M,24M) Qg  bf16 [32][2048][64]  (scaled incl log2e)
//   [24M,32M) Kg  bf16 [32][2048][64]
//   [32M,40M) VTg bf16 [32][64][2048]
// ---------------------------------------------------------------------------
extern "C" void kernel_launch(void* const* d_in, const int* in_sizes, int n_in,
                              void* d_out, int out_size, void* d_ws, size_t ws_size,
                              hipStream_t stream) {
    const float* x   = (const float*)d_in[0];
    const int*  dmask = (const int*)d_in[1];
    const float* Wq = (const float*)d_in[2];
    const float* bq = (const float*)d_in[3];
    const float* Wk = (const float*)d_in[4];
    const float* bk = (const float*)d_in[5];
    const float* Wv = (const float*)d_in[6];
    const float* bv = (const float*)d_in[7];
    const float* Wp = (const float*)d_in[8];
    const float* bp = (const float*)d_in[9];
    float* out = (float*)d_out;
    char* ws = (char*)d_ws;
    u16* xb  = (u16*)(ws);
    u16* wt  = (u16*)(ws + ((size_t)8 << 20));
    u16* Qg  = (u16*)(ws + ((size_t)16 << 20));
    u16* Kg  = (u16*)(ws + ((size_t)24 << 20));
    u16* VTg = (u16*)(ws + ((size_t)32 << 20));
    u16* Og  = xb;   // reuse: xb consumed by qkv_gemm before attn writes Og

    convert_x_k<<<dim3(4096), dim3(256), 0, stream>>>((const float4*)x, (ushort4*)xb, (Bb * Tt * Dd) / 4);
    transpose_w_k<<<dim3(32, 32, 4), dim3(32, 8), 0, stream>>>(Wq, Wk, Wv, Wp, wt);
    qkv_gemm_k<<<dim3(24, 32), dim3(256), 0, stream>>>(xb, wt, bq, bk, bv, Qg, Kg, VTg);
    attn_k<<<dim3(32, 32), dim3(256), 0, stream>>>(Qg, Kg, VTg, dmask, Og);
    out_gemm_k<<<dim3(8, 32), dim3(256), 0, stream>>>(Og, wt + (size_t)3 * Dd * Dd, bp, dmask, out);
}